// Round 4
// baseline (3891.275 us; speedup 1.0000x reference)
//
#include <hip/hip_runtime.h>
#include <stdint.h>

// ---------------------------------------------------------------------------
// HierarchicalReasoningEncoder on MI355X (gfx950).
// fp32 I/O. GEMMs: hi/lo-split bf16 MFMA (3-term, err ~2^-16). Recurrence:
// fp32 state/inputs, W_hh single-bf16 (the only real approximation).
// Workspace kept ~131 MB: xp chunked over time (4x32 steps), token features
// read directly from fp32 with in-register hi/lo split, attention score
// fused into the GEMM epilogue (atomicAdd) so u is never materialized.
// ---------------------------------------------------------------------------

using uint32  = unsigned int;
using bf16x8  = __attribute__((ext_vector_type(8))) __bf16;
using floatx4 = __attribute__((ext_vector_type(4))) float;

union U4B { uint4 u; bf16x8 v; };

__device__ __forceinline__ float b2f(unsigned short u) {
    union { uint32 i; float f; } v; v.i = ((uint32)u) << 16; return v.f;
}
__device__ __forceinline__ unsigned short f2b(float f) {
    union { float f; uint32 i; } v; v.f = f;
    uint32 r = v.i + 0x7fffu + ((v.i >> 16) & 1u);   // RNE
    return (unsigned short)(r >> 16);
}
__device__ __forceinline__ float sigmoidf_(float x) { return 1.f / (1.f + __expf(-x)); }
__device__ __forceinline__ float tanhf_(float x) {
    x = fminf(15.f, fmaxf(-15.f, x));
    float e = __expf(2.f * x);
    return (e - 1.f) / (e + 1.f);
}
__device__ __forceinline__ void unpack8(const uint32* u, float* w) {
    #pragma unroll
    for (int q = 0; q < 4; ++q) {
        union { uint32 i; float f; } cv;
        cv.i = u[q] << 16;          w[2*q]   = cv.f;
        cv.i = u[q] & 0xffff0000u;  w[2*q+1] = cv.f;
    }
}

// ---------------------------------------------------------------------------
// Workspace layout (bytes). Total ~130.7 MB (round-2's 175 MB ran OK).
// ---------------------------------------------------------------------------
#define O_XPC     0L            // 2*256*32*768*4 = 50331648 (chunked xp, fp32)
#define O_OWHI    50331648L     // 32768*512*2 = 33554432
#define O_OWLO    83886080L
#define O_STATE   117440512L    // 2*256*256*4 = 524288
#define O_SCW     117964800L    // 32768*4 = 131072
#define O_W0HI    118095872L    // w_wih_f hi (786432 B each from here)
#define O_W0LO    118882304L
#define O_W1HI    119668736L
#define O_W1LO    120455168L
#define O_WAHI    121241600L    // w_attn_w hi (524288 B)
#define O_WALO    121765888L
#define O_S0HI    122290176L
#define O_S0LO    123076608L
#define O_S1HI    123863040L
#define O_S1LO    124649472L
#define O_SAHI    125435904L
#define O_SALO    125960192L
#define O_HW0     126484480L    // W_hh bf16 (393216 B each)
#define O_HW1     126877696L
#define O_HS0     127270912L
#define O_HS1     127664128L
#define O_SENTHI  128057344L    // 256*512*2 = 262144
#define O_SENTLO  128319488L
#define O_XPS     128581632L    // 2*16*16*768*4 = 1572864
#define O_SSTATE  130154496L    // 2*16*256*4 = 32768
#define O_OSHI    130187264L    // 262144
#define O_OSLO    130449408L
#define O_SCS     130711552L    // 1024
// end ~130712576

// ---------------------------------------------------------------------------
// Weight prep: fp32 -> bf16 hi/lo (RNE both), 6 matrices, one launch.
// Each block converts 2048 elems. Block ranges hardcoded.
// ---------------------------------------------------------------------------
__global__ __launch_bounds__(256)
void cvt_hilo6(const float* __restrict__ s0, const float* __restrict__ s1,
               const float* __restrict__ s2, const float* __restrict__ s3,
               const float* __restrict__ s4, const float* __restrict__ s5,
               char* __restrict__ ws)
{
    const int b = blockIdx.x;
    const float* src; unsigned short *hi, *lo; int base;
    if (b < 192)      { src = s0; hi = (unsigned short*)(ws + O_W0HI); lo = (unsigned short*)(ws + O_W0LO); base = b; }
    else if (b < 384) { src = s1; hi = (unsigned short*)(ws + O_W1HI); lo = (unsigned short*)(ws + O_W1LO); base = b - 192; }
    else if (b < 576) { src = s2; hi = (unsigned short*)(ws + O_S0HI); lo = (unsigned short*)(ws + O_S0LO); base = b - 384; }
    else if (b < 768) { src = s3; hi = (unsigned short*)(ws + O_S1HI); lo = (unsigned short*)(ws + O_S1LO); base = b - 576; }
    else if (b < 896) { src = s4; hi = (unsigned short*)(ws + O_WAHI); lo = (unsigned short*)(ws + O_WALO); base = b - 768; }
    else              { src = s5; hi = (unsigned short*)(ws + O_SAHI); lo = (unsigned short*)(ws + O_SALO); base = b - 896; }
    const int idx = (base * 256 + threadIdx.x) * 8;
    float f[8];
    *reinterpret_cast<float4*>(&f[0]) = *reinterpret_cast<const float4*>(src + idx);
    *reinterpret_cast<float4*>(&f[4]) = *reinterpret_cast<const float4*>(src + idx + 4);
    unsigned short h[8], l[8];
    #pragma unroll
    for (int j = 0; j < 8; ++j) {
        h[j] = f2b(f[j]);
        l[j] = f2b(f[j] - b2f(h[j]));
    }
    *reinterpret_cast<uint4*>(hi + idx) = *reinterpret_cast<const uint4*>(h);
    *reinterpret_cast<uint4*>(lo + idx) = *reinterpret_cast<const uint4*>(l);
}

// W_hh fp32 -> single bf16, 4 matrices, one launch (96 blocks each).
__global__ __launch_bounds__(256)
void cvt_b4(const float* __restrict__ s0, const float* __restrict__ s1,
            const float* __restrict__ s2, const float* __restrict__ s3,
            char* __restrict__ ws)
{
    const int b = blockIdx.x;
    const float* src; unsigned short* dst; int base;
    if (b < 96)       { src = s0; dst = (unsigned short*)(ws + O_HW0); base = b; }
    else if (b < 192) { src = s1; dst = (unsigned short*)(ws + O_HW1); base = b - 96; }
    else if (b < 288) { src = s2; dst = (unsigned short*)(ws + O_HS0); base = b - 192; }
    else              { src = s3; dst = (unsigned short*)(ws + O_HS1); base = b - 288; }
    const int idx = (base * 256 + threadIdx.x) * 8;
    float f[8];
    *reinterpret_cast<float4*>(&f[0]) = *reinterpret_cast<const float4*>(src + idx);
    *reinterpret_cast<float4*>(&f[4]) = *reinterpret_cast<const float4*>(src + idx + 4);
    unsigned short o[8];
    #pragma unroll
    for (int j = 0; j < 8; ++j) o[j] = f2b(f[j]);
    *reinterpret_cast<uint4*>(dst + idx) = *reinterpret_cast<const uint4*>(o);
}

// ---------------------------------------------------------------------------
// GEMM: C[m][n] = sum_k A[m][k]*W[n][k] (+bias). K=512 fixed. W is bf16 hi/lo;
// A is fp32 (in-register truncation split) or bf16 hi/lo. 3-term MFMA.
// Block 256 = 4 waves; tile 64(M) x 64(N). MFMA 16x16x32 bf16 layouts:
// A/B: idx=lane&15, k=(lane>>4)*8+j ; D: col=lane&15, row=(lane>>4)*4+reg.
// AMODE 1: A fp32 token_feats, row map n=m>>5,t=t0+sgn*(m&31): ((n&15)*128+t)*16+(n>>4)
// AMODE 2: A bf16 hi/lo, arow = mrow
// AMODE 3: A bf16 hi/lo, row map n=m>>4, arow = n*16 + t0+sgn*(m&15)
// OUT 0: C[mrow*ldC+n] = acc + bias[n]   (fp32)
// OUT 1: score[mrow] += sum_n ctx[n]*tanh(acc + bias[n])  (atomic, fused attn)
// ---------------------------------------------------------------------------
template<int AMODE, int OUT>
__global__ __launch_bounds__(256)
void gemm(const void* __restrict__ Ap, const void* __restrict__ Ap2,
          const unsigned short* __restrict__ Whi, const unsigned short* __restrict__ Wlo,
          const float* __restrict__ bias,
          float* __restrict__ C, int ldC,
          float* __restrict__ score, const float* __restrict__ ctx,
          int ldA, int t0, int sgn)
{
    const int lane = threadIdx.x & 63;
    const int wave = threadIdx.x >> 6;
    const int m_base = blockIdx.y * 64 + wave * 16;
    const int n_base = blockIdx.x * 64;
    const int kfrag = (lane >> 4) * 8;
    const int mrow = m_base + (lane & 15);

    long arow;
    if (AMODE == 1) {
        const int n = mrow >> 5, tl = mrow & 31;
        const int t = t0 + sgn * tl;
        arow = (long)(((n & 15) * 128 + t) * 16 + (n >> 4));
    } else if (AMODE == 3) {
        const int n = mrow >> 4, tl = mrow & 15;
        arow = (long)(n * 16 + t0 + sgn * tl);
    } else {
        arow = mrow;
    }
    const long abase = arow * ldA + kfrag;
    const int ncol = n_base + (lane & 15);

    floatx4 acc[4];
    #pragma unroll
    for (int nt = 0; nt < 4; ++nt) acc[nt] = (floatx4){0.f, 0.f, 0.f, 0.f};

    for (int k0 = 0; k0 < 512; k0 += 32) {
        bf16x8 ah, al;
        if (AMODE == 1) {
            const float* A = (const float*)Ap;
            uint4 ua = *reinterpret_cast<const uint4*>(A + abase + k0);
            uint4 ub = *reinterpret_cast<const uint4*>(A + abase + k0 + 4);
            U4B H, L;
            H.u.x = (ua.x >> 16) | (ua.y & 0xffff0000u);
            H.u.y = (ua.z >> 16) | (ua.w & 0xffff0000u);
            H.u.z = (ub.x >> 16) | (ub.y & 0xffff0000u);
            H.u.w = (ub.z >> 16) | (ub.w & 0xffff0000u);
            uint32 lw[8];
            lw[0] = __float_as_uint(__uint_as_float(ua.x) - __uint_as_float(ua.x & 0xffff0000u));
            lw[1] = __float_as_uint(__uint_as_float(ua.y) - __uint_as_float(ua.y & 0xffff0000u));
            lw[2] = __float_as_uint(__uint_as_float(ua.z) - __uint_as_float(ua.z & 0xffff0000u));
            lw[3] = __float_as_uint(__uint_as_float(ua.w) - __uint_as_float(ua.w & 0xffff0000u));
            lw[4] = __float_as_uint(__uint_as_float(ub.x) - __uint_as_float(ub.x & 0xffff0000u));
            lw[5] = __float_as_uint(__uint_as_float(ub.y) - __uint_as_float(ub.y & 0xffff0000u));
            lw[6] = __float_as_uint(__uint_as_float(ub.z) - __uint_as_float(ub.z & 0xffff0000u));
            lw[7] = __float_as_uint(__uint_as_float(ub.w) - __uint_as_float(ub.w & 0xffff0000u));
            L.u.x = (lw[0] >> 16) | (lw[1] & 0xffff0000u);
            L.u.y = (lw[2] >> 16) | (lw[3] & 0xffff0000u);
            L.u.z = (lw[4] >> 16) | (lw[5] & 0xffff0000u);
            L.u.w = (lw[6] >> 16) | (lw[7] & 0xffff0000u);
            ah = H.v; al = L.v;
        } else {
            const unsigned short* Ahi = (const unsigned short*)Ap;
            const unsigned short* Alo = (const unsigned short*)Ap2;
            ah = *reinterpret_cast<const bf16x8*>(Ahi + abase + k0);
            al = *reinterpret_cast<const bf16x8*>(Alo + abase + k0);
        }
        #pragma unroll
        for (int nt = 0; nt < 4; ++nt) {
            const long wk = (long)(ncol + nt * 16) * 512 + k0 + kfrag;
            bf16x8 wh = *reinterpret_cast<const bf16x8*>(Whi + wk);
            bf16x8 wl = *reinterpret_cast<const bf16x8*>(Wlo + wk);
            acc[nt] = __builtin_amdgcn_mfma_f32_16x16x32_bf16(ah, wh, acc[nt], 0, 0, 0);
            acc[nt] = __builtin_amdgcn_mfma_f32_16x16x32_bf16(ah, wl, acc[nt], 0, 0, 0);
            acc[nt] = __builtin_amdgcn_mfma_f32_16x16x32_bf16(al, wh, acc[nt], 0, 0, 0);
        }
    }

    const int col = lane & 15;
    const int rbase = (lane >> 4) * 4;
    if (OUT == 0) {
        #pragma unroll
        for (int nt = 0; nt < 4; ++nt) {
            const int n = n_base + nt * 16 + col;
            const float bs = bias[n];
            #pragma unroll
            for (int r = 0; r < 4; ++r) {
                const int m = m_base + rbase + r;
                C[(long)m * ldC + n] = acc[nt][r] + bs;
            }
        }
    } else {
        float p[4] = {0.f, 0.f, 0.f, 0.f};
        #pragma unroll
        for (int nt = 0; nt < 4; ++nt) {
            const int n = n_base + nt * 16 + col;
            const float cx = ctx[n];
            const float bs = bias[n];
            #pragma unroll
            for (int r = 0; r < 4; ++r)
                p[r] += cx * tanhf_(acc[nt][r] + bs);
        }
        #pragma unroll
        for (int mk = 8; mk > 0; mk >>= 1) {
            #pragma unroll
            for (int r = 0; r < 4; ++r) p[r] += __shfl_xor(p[r], mk, 16);
        }
        if (col == 0) {
            #pragma unroll
            for (int r = 0; r < 4; ++r)
                atomicAdd(&score[m_base + rbase + r], p[r]);
        }
    }
}

// ---------------------------------------------------------------------------
// GRU recurrence chunk. Grid = 2*groups WGs of 256; WG = 4 seqs, one dir.
// Thread j owns hidden unit j: streams bf16 W rows j,j+256,j+512 from L2;
// h fp32 in LDS; h state persists in global across chunk launches.
// xp fp32 laid out [dir][seq][st][768] (st = local step). Out: bf16 hi/lo,
// row n*Tout + t_global, col dir*256 + tid.
// ---------------------------------------------------------------------------
__global__ __launch_bounds__(256)
void gru_chunk(const float* __restrict__ xp,
               const unsigned short* __restrict__ Wf,
               const unsigned short* __restrict__ Wb,
               const float* __restrict__ bhf, const float* __restrict__ bhb,
               float* __restrict__ state,
               unsigned short* __restrict__ ohi, unsigned short* __restrict__ olo,
               int steps, int t0f, int t0b, int groups, int Tout)
{
    const int tid = threadIdx.x;
    const int dir = blockIdx.x / groups;
    const int g = blockIdx.x % groups;
    const int nseq = groups * 4;
    const unsigned short* W = dir ? Wb : Wf;
    const float* bh = dir ? bhb : bhf;

    __shared__ __align__(16) float hs[4][256];
    #pragma unroll
    for (int s = 0; s < 4; ++s)
        hs[s][tid] = state[((long)dir * nseq + (g * 4 + s)) * 256 + tid];

    const float bhr = bh[tid];
    const float bhz = bh[tid + 256];
    const float bhn = bh[tid + 512];

    const unsigned short* wr = W + (long)tid * 256;
    const unsigned short* wz = W + (long)(tid + 256) * 256;
    const unsigned short* wn = W + (long)(tid + 512) * 256;

    const float* xbase = xp + (long)dir * nseq * steps * 768;

    __syncthreads();

    for (int st = 0; st < steps; ++st) {
        const int t = dir ? (t0b - st) : (t0f + st);
        float ar[4] = {0.f, 0.f, 0.f, 0.f};
        float az[4] = {0.f, 0.f, 0.f, 0.f};
        float an[4] = {0.f, 0.f, 0.f, 0.f};
        for (int k = 0; k < 256; k += 8) {
            uint32 ur[4], uz[4], un[4];
            *reinterpret_cast<uint4*>(ur) = *reinterpret_cast<const uint4*>(wr + k);
            *reinterpret_cast<uint4*>(uz) = *reinterpret_cast<const uint4*>(wz + k);
            *reinterpret_cast<uint4*>(un) = *reinterpret_cast<const uint4*>(wn + k);
            float fr[8], fz[8], fn[8];
            unpack8(ur, fr); unpack8(uz, fz); unpack8(un, fn);
            #pragma unroll
            for (int s = 0; s < 4; ++s) {
                float hv[8];
                *reinterpret_cast<float4*>(&hv[0]) = *reinterpret_cast<const float4*>(&hs[s][k]);
                *reinterpret_cast<float4*>(&hv[4]) = *reinterpret_cast<const float4*>(&hs[s][k + 4]);
                #pragma unroll
                for (int e = 0; e < 8; ++e) {
                    ar[s] += fr[e] * hv[e];
                    az[s] += fz[e] * hv[e];
                    an[s] += fn[e] * hv[e];
                }
            }
        }
        float hnew[4];
        #pragma unroll
        for (int s = 0; s < 4; ++s) {
            const float* x = xbase + ((long)(g * 4 + s) * steps + st) * 768 + tid;
            const float r  = sigmoidf_(x[0]   + ar[s] + bhr);
            const float z  = sigmoidf_(x[256] + az[s] + bhz);
            const float nn = tanhf_(x[512] + r * (an[s] + bhn));
            hnew[s] = (1.f - z) * nn + z * hs[s][tid];
        }
        #pragma unroll
        for (int s = 0; s < 4; ++s) {
            const long o = ((long)(g * 4 + s) * Tout + t) * 512 + dir * 256 + tid;
            const unsigned short h = f2b(hnew[s]);
            ohi[o] = h;
            olo[o] = f2b(hnew[s] - b2f(h));
        }
        __syncthreads();
        #pragma unroll
        for (int s = 0; s < 4; ++s) hs[s][tid] = hnew[s];
        __syncthreads();
    }

    #pragma unroll
    for (int s = 0; s < 4; ++s)
        state[((long)dir * nseq + (g * 4 + s)) * 256 + tid] = hs[s][tid];
}

// ---------------------------------------------------------------------------
// outv[n][:] = sum_t softmax(score[n*T..])_t * feats[n*T+t][:]  (H=512, fp32)
// feats = bf16 hi/lo (exact fp32). MODE 0: write bf16 hi/lo. MODE 1: fp32.
// ---------------------------------------------------------------------------
template<int MODE>
__global__ __launch_bounds__(256)
void attn_wsum(const float* __restrict__ score,
               const unsigned short* __restrict__ fhi,
               const unsigned short* __restrict__ flo,
               void* __restrict__ o1, void* __restrict__ o2, int T)
{
    const int n = blockIdx.x;
    const int tid = threadIdx.x;
    __shared__ float a[128];
    if (tid < T) a[tid] = score[n * T + tid];
    __syncthreads();
    float mx = -1e30f;
    for (int t = 0; t < T; ++t) mx = fmaxf(mx, a[t]);
    float sm = 0.f;
    for (int t = 0; t < T; ++t) sm += __expf(a[t] - mx);
    const float inv = 1.f / sm;
    float acc0 = 0.f, acc1 = 0.f;
    for (int t = 0; t < T; ++t) {
        const float w = __expf(a[t] - mx) * inv;
        const long base = ((long)n * T + t) * 512;
        acc0 += w * (b2f(fhi[base + tid])       + b2f(flo[base + tid]));
        acc1 += w * (b2f(fhi[base + tid + 256]) + b2f(flo[base + tid + 256]));
    }
    if (MODE == 1) {
        float* o = (float*)o1;
        o[n * 512 + tid] = acc0;
        o[n * 512 + tid + 256] = acc1;
    } else {
        unsigned short* oh = (unsigned short*)o1;
        unsigned short* ol = (unsigned short*)o2;
        const unsigned short h0 = f2b(acc0), h1 = f2b(acc1);
        oh[n * 512 + tid]       = h0;  ol[n * 512 + tid]       = f2b(acc0 - b2f(h0));
        oh[n * 512 + tid + 256] = h1;  ol[n * 512 + tid + 256] = f2b(acc1 - b2f(h1));
    }
}

extern "C" void kernel_launch(void* const* d_in, const int* in_sizes, int n_in,
                              void* d_out, int out_size, void* d_ws, size_t ws_size,
                              hipStream_t stream) {
    const float* tok      = (const float*)d_in[0];
    const float* w_wih_f  = (const float*)d_in[2];
    const float* w_whh_f  = (const float*)d_in[3];
    const float* w_bih_f  = (const float*)d_in[4];
    const float* w_bhh_f  = (const float*)d_in[5];
    const float* w_wih_b  = (const float*)d_in[6];
    const float* w_whh_b  = (const float*)d_in[7];
    const float* w_bih_b  = (const float*)d_in[8];
    const float* w_bhh_b  = (const float*)d_in[9];
    const float* s_wih_f  = (const float*)d_in[10];
    const float* s_whh_f  = (const float*)d_in[11];
    const float* s_bih_f  = (const float*)d_in[12];
    const float* s_bhh_f  = (const float*)d_in[13];
    const float* s_wih_b  = (const float*)d_in[14];
    const float* s_whh_b  = (const float*)d_in[15];
    const float* s_bih_b  = (const float*)d_in[16];
    const float* s_bhh_b  = (const float*)d_in[17];
    // w_attn_w=18, w_attn_b=19, w_ctx=20, s_attn_w=21, s_attn_b=22, s_ctx=23
    const float* w_attn_b = (const float*)d_in[19];
    const float* w_ctx    = (const float*)d_in[20];
    const float* s_attn_b = (const float*)d_in[22];
    const float* s_ctx    = (const float*)d_in[23];

    char* ws = (char*)d_ws;
    float*          xpc   = (float*)(ws + O_XPC);
    unsigned short* owhi  = (unsigned short*)(ws + O_OWHI);
    unsigned short* owlo  = (unsigned short*)(ws + O_OWLO);
    float*          state = (float*)(ws + O_STATE);
    float*          score_w = (float*)(ws + O_SCW);
    unsigned short* W0HI  = (unsigned short*)(ws + O_W0HI);
    unsigned short* W0LO  = (unsigned short*)(ws + O_W0LO);
    unsigned short* W1HI  = (unsigned short*)(ws + O_W1HI);
    unsigned short* W1LO  = (unsigned short*)(ws + O_W1LO);
    unsigned short* WAHI  = (unsigned short*)(ws + O_WAHI);
    unsigned short* WALO  = (unsigned short*)(ws + O_WALO);
    unsigned short* S0HI  = (unsigned short*)(ws + O_S0HI);
    unsigned short* S0LO  = (unsigned short*)(ws + O_S0LO);
    unsigned short* S1HI  = (unsigned short*)(ws + O_S1HI);
    unsigned short* S1LO  = (unsigned short*)(ws + O_S1LO);
    unsigned short* SAHI  = (unsigned short*)(ws + O_SAHI);
    unsigned short* SALO  = (unsigned short*)(ws + O_SALO);
    unsigned short* HW0   = (unsigned short*)(ws + O_HW0);
    unsigned short* HW1   = (unsigned short*)(ws + O_HW1);
    unsigned short* HS0   = (unsigned short*)(ws + O_HS0);
    unsigned short* HS1   = (unsigned short*)(ws + O_HS1);
    unsigned short* senthi = (unsigned short*)(ws + O_SENTHI);
    unsigned short* sentlo = (unsigned short*)(ws + O_SENTLO);
    float*          xp_s  = (float*)(ws + O_XPS);
    float*          sstate = (float*)(ws + O_SSTATE);
    unsigned short* oshi  = (unsigned short*)(ws + O_OSHI);
    unsigned short* oslo  = (unsigned short*)(ws + O_OSLO);
    float*          score_s = (float*)(ws + O_SCS);

    const dim3 blk(256);

    // Zero-init: GRU h states and atomic score accumulators (ws is poisoned).
    hipMemsetAsync(ws + O_STATE,  0, 524288, stream);
    hipMemsetAsync(ws + O_SSTATE, 0, 32768, stream);
    hipMemsetAsync(ws + O_SCW,    0, 131072, stream);
    hipMemsetAsync(ws + O_SCS,    0, 1024, stream);

    // Weight prep (one launch each).
    cvt_hilo6<<<dim3(1024), blk, 0, stream>>>(w_wih_f, w_wih_b, s_wih_f, s_wih_b,
                                              (const float*)d_in[18], (const float*)d_in[21], ws);
    cvt_b4<<<dim3(384), blk, 0, stream>>>(w_whh_f, w_whh_b, s_whh_f, s_whh_b, ws);

    // Word level: 4 time-chunks of 32 steps. Per chunk: input-gate GEMM for
    // fwd rows [32c,32c+32) and bwd rows [127-32c .. 96-32c], then GRU chunk.
    const long XDW = 256L * 32 * 768;   // per-dir xpc stride (floats)
    for (int c = 0; c < 4; ++c) {
        gemm<1, 0><<<dim3(12, 128), blk, 0, stream>>>(
            tok, nullptr, W0HI, W0LO, w_bih_f, xpc, 768, nullptr, nullptr,
            512, 32 * c, 1);
        gemm<1, 0><<<dim3(12, 128), blk, 0, stream>>>(
            tok, nullptr, W1HI, W1LO, w_bih_b, xpc + XDW, 768, nullptr, nullptr,
            512, 127 - 32 * c, -1);
        gru_chunk<<<dim3(128), blk, 0, stream>>>(
            xpc, HW0, HW1, w_bhh_f, w_bhh_b, state, owhi, owlo,
            32, 32 * c, 127 - 32 * c, 64, 128);
    }

    // Word attention: fused u-GEMM + tanh·ctx score (atomic), then softmax+wsum.
    gemm<2, 1><<<dim3(8, 512), blk, 0, stream>>>(
        owhi, owlo, WAHI, WALO, w_attn_b, nullptr, 0, score_w, w_ctx, 512, 0, 1);
    attn_wsum<0><<<dim3(256), blk, 0, stream>>>(score_w, owhi, owlo, senthi, sentlo, 128);

    // Sentence input gates: per dir, M = 16 seqs x 16 steps (time-remapped A).
    const long XDS = 16L * 16 * 768;
    gemm<3, 0><<<dim3(12, 4), blk, 0, stream>>>(
        senthi, sentlo, S0HI, S0LO, s_bih_f, xp_s, 768, nullptr, nullptr,
        512, 0, 1);
    gemm<3, 0><<<dim3(12, 4), blk, 0, stream>>>(
        senthi, sentlo, S1HI, S1LO, s_bih_b, xp_s + XDS, 768, nullptr, nullptr,
        512, 15, -1);

    // Sentence BiGRU: 16 seqs, T=16, one chunk.
    gru_chunk<<<dim3(8), blk, 0, stream>>>(
        xp_s, HS0, HS1, s_bhh_f, s_bhh_b, sstate, oshi, oslo,
        16, 0, 15, 4, 16);

    // Sentence attention -> d_out (16 x 512 fp32).
    gemm<2, 1><<<dim3(8, 4), blk, 0, stream>>>(
        oshi, oslo, SAHI, SALO, s_attn_b, nullptr, 0, score_s, s_ctx, 512, 0, 1);
    attn_wsum<1><<<dim3(16), blk, 0, stream>>>(score_s, oshi, oslo, d_out, nullptr, 16);
}

// Round 5
// 2299.950 us; speedup vs baseline: 1.6919x; 1.6919x over previous
//
#include <hip/hip_runtime.h>
#include <stdint.h>

// ---------------------------------------------------------------------------
// HierarchicalReasoningEncoder on MI355X (gfx950).
// fp32 I/O. GEMMs: hi/lo-split bf16 MFMA (3-term, err ~2^-16). Recurrence:
// register-resident W_hh (bf16, the only approximation) + MFMA gates;
// h state fp32 in LDS, h dot-operand as bf16 hi/lo (exact to 2^-16).
// Workspace ~131 MB: xp chunked over time (4x32 steps), token features read
// directly from fp32 with in-register hi/lo split, attention score fused
// into the GEMM epilogue (atomicAdd) so u is never materialized.
// ---------------------------------------------------------------------------

using uint32  = unsigned int;
using bf16x8  = __attribute__((ext_vector_type(8))) __bf16;
using floatx4 = __attribute__((ext_vector_type(4))) float;

union U4B { uint4 u; bf16x8 v; };

__device__ __forceinline__ float b2f(unsigned short u) {
    union { uint32 i; float f; } v; v.i = ((uint32)u) << 16; return v.f;
}
__device__ __forceinline__ unsigned short f2b(float f) {
    union { float f; uint32 i; } v; v.f = f;
    uint32 r = v.i + 0x7fffu + ((v.i >> 16) & 1u);   // RNE
    return (unsigned short)(r >> 16);
}
__device__ __forceinline__ float sigmoidf_(float x) { return 1.f / (1.f + __expf(-x)); }
__device__ __forceinline__ float tanhf_(float x) {
    x = fminf(15.f, fmaxf(-15.f, x));
    float e = __expf(2.f * x);
    return (e - 1.f) / (e + 1.f);
}

// ---------------------------------------------------------------------------
// Workspace layout (bytes). Total ~130.7 MB.
// ---------------------------------------------------------------------------
#define O_XPC     0L            // 2*256*32*768*4 = 50331648 (chunked xp, fp32)
#define O_OWHI    50331648L     // 32768*512*2 = 33554432
#define O_OWLO    83886080L
#define O_STATE   117440512L    // 2*256*256*4 = 524288
#define O_SCW     117964800L    // 32768*4 = 131072
#define O_W0HI    118095872L
#define O_W0LO    118882304L
#define O_W1HI    119668736L
#define O_W1LO    120455168L
#define O_WAHI    121241600L
#define O_WALO    121765888L
#define O_S0HI    122290176L
#define O_S0LO    123076608L
#define O_S1HI    123863040L
#define O_S1LO    124649472L
#define O_SAHI    125435904L
#define O_SALO    125960192L
#define O_HW0     126484480L    // W_hh bf16 (393216 B each)
#define O_HW1     126877696L
#define O_HS0     127270912L
#define O_HS1     127664128L
#define O_SENTHI  128057344L
#define O_SENTLO  128319488L
#define O_XPS     128581632L    // 2*16*16*768*4 = 1572864
#define O_SSTATE  130154496L    // 2*16*256*4 = 32768
#define O_OSHI    130187264L
#define O_OSLO    130449408L
#define O_SCS     130711552L

// ---------------------------------------------------------------------------
// Weight prep: fp32 -> bf16 hi/lo, 6 matrices, one launch.
// ---------------------------------------------------------------------------
__global__ __launch_bounds__(256)
void cvt_hilo6(const float* __restrict__ s0, const float* __restrict__ s1,
               const float* __restrict__ s2, const float* __restrict__ s3,
               const float* __restrict__ s4, const float* __restrict__ s5,
               char* __restrict__ ws)
{
    const int b = blockIdx.x;
    const float* src; unsigned short *hi, *lo; int base;
    if (b < 192)      { src = s0; hi = (unsigned short*)(ws + O_W0HI); lo = (unsigned short*)(ws + O_W0LO); base = b; }
    else if (b < 384) { src = s1; hi = (unsigned short*)(ws + O_W1HI); lo = (unsigned short*)(ws + O_W1LO); base = b - 192; }
    else if (b < 576) { src = s2; hi = (unsigned short*)(ws + O_S0HI); lo = (unsigned short*)(ws + O_S0LO); base = b - 384; }
    else if (b < 768) { src = s3; hi = (unsigned short*)(ws + O_S1HI); lo = (unsigned short*)(ws + O_S1LO); base = b - 576; }
    else if (b < 896) { src = s4; hi = (unsigned short*)(ws + O_WAHI); lo = (unsigned short*)(ws + O_WALO); base = b - 768; }
    else              { src = s5; hi = (unsigned short*)(ws + O_SAHI); lo = (unsigned short*)(ws + O_SALO); base = b - 896; }
    const int idx = (base * 256 + threadIdx.x) * 8;
    float f[8];
    *reinterpret_cast<float4*>(&f[0]) = *reinterpret_cast<const float4*>(src + idx);
    *reinterpret_cast<float4*>(&f[4]) = *reinterpret_cast<const float4*>(src + idx + 4);
    unsigned short h[8], l[8];
    #pragma unroll
    for (int j = 0; j < 8; ++j) {
        h[j] = f2b(f[j]);
        l[j] = f2b(f[j] - b2f(h[j]));
    }
    *reinterpret_cast<uint4*>(hi + idx) = *reinterpret_cast<const uint4*>(h);
    *reinterpret_cast<uint4*>(lo + idx) = *reinterpret_cast<const uint4*>(l);
}

// W_hh fp32 -> single bf16, 4 matrices, one launch.
__global__ __launch_bounds__(256)
void cvt_b4(const float* __restrict__ s0, const float* __restrict__ s1,
            const float* __restrict__ s2, const float* __restrict__ s3,
            char* __restrict__ ws)
{
    const int b = blockIdx.x;
    const float* src; unsigned short* dst; int base;
    if (b < 96)       { src = s0; dst = (unsigned short*)(ws + O_HW0); base = b; }
    else if (b < 192) { src = s1; dst = (unsigned short*)(ws + O_HW1); base = b - 96; }
    else if (b < 288) { src = s2; dst = (unsigned short*)(ws + O_HS0); base = b - 192; }
    else              { src = s3; dst = (unsigned short*)(ws + O_HS1); base = b - 288; }
    const int idx = (base * 256 + threadIdx.x) * 8;
    float f[8];
    *reinterpret_cast<float4*>(&f[0]) = *reinterpret_cast<const float4*>(src + idx);
    *reinterpret_cast<float4*>(&f[4]) = *reinterpret_cast<const float4*>(src + idx + 4);
    unsigned short o[8];
    #pragma unroll
    for (int j = 0; j < 8; ++j) o[j] = f2b(f[j]);
    *reinterpret_cast<uint4*>(dst + idx) = *reinterpret_cast<const uint4*>(o);
}

// ---------------------------------------------------------------------------
// GEMM: C[m][n] = sum_k A[m][k]*W[n][k] (+bias). K=512. W bf16 hi/lo; A fp32
// (in-register split) or bf16 hi/lo. 3-term MFMA. Tile 64x64, 4 waves.
// AMODE 1: A fp32 token_feats row map; AMODE 2: A hi/lo row-major;
// AMODE 3: A hi/lo with sentence time remap.
// OUT 0: fp32 C; OUT 1: fused attn score (atomicAdd of sum ctx*tanh).
// ---------------------------------------------------------------------------
template<int AMODE, int OUT>
__global__ __launch_bounds__(256)
void gemm(const void* __restrict__ Ap, const void* __restrict__ Ap2,
          const unsigned short* __restrict__ Whi, const unsigned short* __restrict__ Wlo,
          const float* __restrict__ bias,
          float* __restrict__ C, int ldC,
          float* __restrict__ score, const float* __restrict__ ctx,
          int ldA, int t0, int sgn)
{
    const int lane = threadIdx.x & 63;
    const int wave = threadIdx.x >> 6;
    const int m_base = blockIdx.y * 64 + wave * 16;
    const int n_base = blockIdx.x * 64;
    const int kfrag = (lane >> 4) * 8;
    const int mrow = m_base + (lane & 15);

    long arow;
    if (AMODE == 1) {
        const int n = mrow >> 5, tl = mrow & 31;
        const int t = t0 + sgn * tl;
        arow = (long)(((n & 15) * 128 + t) * 16 + (n >> 4));
    } else if (AMODE == 3) {
        const int n = mrow >> 4, tl = mrow & 15;
        arow = (long)(n * 16 + t0 + sgn * tl);
    } else {
        arow = mrow;
    }
    const long abase = arow * ldA + kfrag;
    const int ncol = n_base + (lane & 15);

    floatx4 acc[4];
    #pragma unroll
    for (int nt = 0; nt < 4; ++nt) acc[nt] = (floatx4){0.f, 0.f, 0.f, 0.f};

    for (int k0 = 0; k0 < 512; k0 += 32) {
        bf16x8 ah, al;
        if (AMODE == 1) {
            const float* A = (const float*)Ap;
            uint4 ua = *reinterpret_cast<const uint4*>(A + abase + k0);
            uint4 ub = *reinterpret_cast<const uint4*>(A + abase + k0 + 4);
            U4B H, L;
            H.u.x = (ua.x >> 16) | (ua.y & 0xffff0000u);
            H.u.y = (ua.z >> 16) | (ua.w & 0xffff0000u);
            H.u.z = (ub.x >> 16) | (ub.y & 0xffff0000u);
            H.u.w = (ub.z >> 16) | (ub.w & 0xffff0000u);
            uint32 lw[8];
            lw[0] = __float_as_uint(__uint_as_float(ua.x) - __uint_as_float(ua.x & 0xffff0000u));
            lw[1] = __float_as_uint(__uint_as_float(ua.y) - __uint_as_float(ua.y & 0xffff0000u));
            lw[2] = __float_as_uint(__uint_as_float(ua.z) - __uint_as_float(ua.z & 0xffff0000u));
            lw[3] = __float_as_uint(__uint_as_float(ua.w) - __uint_as_float(ua.w & 0xffff0000u));
            lw[4] = __float_as_uint(__uint_as_float(ub.x) - __uint_as_float(ub.x & 0xffff0000u));
            lw[5] = __float_as_uint(__uint_as_float(ub.y) - __uint_as_float(ub.y & 0xffff0000u));
            lw[6] = __float_as_uint(__uint_as_float(ub.z) - __uint_as_float(ub.z & 0xffff0000u));
            lw[7] = __float_as_uint(__uint_as_float(ub.w) - __uint_as_float(ub.w & 0xffff0000u));
            L.u.x = (lw[0] >> 16) | (lw[1] & 0xffff0000u);
            L.u.y = (lw[2] >> 16) | (lw[3] & 0xffff0000u);
            L.u.z = (lw[4] >> 16) | (lw[5] & 0xffff0000u);
            L.u.w = (lw[6] >> 16) | (lw[7] & 0xffff0000u);
            ah = H.v; al = L.v;
        } else {
            const unsigned short* Ahi = (const unsigned short*)Ap;
            const unsigned short* Alo = (const unsigned short*)Ap2;
            ah = *reinterpret_cast<const bf16x8*>(Ahi + abase + k0);
            al = *reinterpret_cast<const bf16x8*>(Alo + abase + k0);
        }
        #pragma unroll
        for (int nt = 0; nt < 4; ++nt) {
            const long wk = (long)(ncol + nt * 16) * 512 + k0 + kfrag;
            bf16x8 wh = *reinterpret_cast<const bf16x8*>(Whi + wk);
            bf16x8 wl = *reinterpret_cast<const bf16x8*>(Wlo + wk);
            acc[nt] = __builtin_amdgcn_mfma_f32_16x16x32_bf16(ah, wh, acc[nt], 0, 0, 0);
            acc[nt] = __builtin_amdgcn_mfma_f32_16x16x32_bf16(ah, wl, acc[nt], 0, 0, 0);
            acc[nt] = __builtin_amdgcn_mfma_f32_16x16x32_bf16(al, wh, acc[nt], 0, 0, 0);
        }
    }

    const int col = lane & 15;
    const int rbase = (lane >> 4) * 4;
    if (OUT == 0) {
        #pragma unroll
        for (int nt = 0; nt < 4; ++nt) {
            const int n = n_base + nt * 16 + col;
            const float bs = bias[n];
            #pragma unroll
            for (int r = 0; r < 4; ++r) {
                const int m = m_base + rbase + r;
                C[(long)m * ldC + n] = acc[nt][r] + bs;
            }
        }
    } else {
        float p[4] = {0.f, 0.f, 0.f, 0.f};
        #pragma unroll
        for (int nt = 0; nt < 4; ++nt) {
            const int n = n_base + nt * 16 + col;
            const float cx = ctx[n];
            const float bs = bias[n];
            #pragma unroll
            for (int r = 0; r < 4; ++r)
                p[r] += cx * tanhf_(acc[nt][r] + bs);
        }
        #pragma unroll
        for (int mk = 8; mk > 0; mk >>= 1) {
            #pragma unroll
            for (int r = 0; r < 4; ++r) p[r] += __shfl_xor(p[r], mk, 16);
        }
        if (col == 0) {
            #pragma unroll
            for (int r = 0; r < 4; ++r)
                atomicAdd(&score[m_base + rbase + r], p[r]);
        }
    }
}

// ---------------------------------------------------------------------------
// GRU recurrence with register-resident W_hh (bf16) + MFMA gates.
// WG = 512 thr = 8 waves; 16 seqs of one direction per WG. Wave w holds W_hh
// rows [w*96, w*96+96) as 48 MFMA A-fragments (192 VGPR). Per step:
//   MFMA phase: pre[768][16] = W_hh @ (h_hi + h_lo)  (96 MFMA/wave)
//   elementwise: gates + h update; writes h state (fp32 LDS), swizzled bf16
//   hi/lo B-fragment buffers (conflict-free ds_read_b128 next step), out.
// xp fp32 [dir][seq][st][768]; out bf16 hi/lo row seq*Tout+t, col dir*256+j.
// Chunk-persistent state in global.
// ---------------------------------------------------------------------------
__global__ __launch_bounds__(512, 2)
void gru_reg(const float* __restrict__ xp,
             const unsigned short* __restrict__ Wf,
             const unsigned short* __restrict__ Wb,
             const float* __restrict__ bhf, const float* __restrict__ bhb,
             float* __restrict__ state,
             unsigned short* __restrict__ ohi, unsigned short* __restrict__ olo,
             int steps, int t0f, int t0b, int groups, int Tout)
{
    extern __shared__ char smem[];
    float* pre    = (float*)smem;                          // [768][17] f32
    float* hstate = (float*)(smem + 52224);                // [256][17] f32
    unsigned short* Bhi = (unsigned short*)(smem + 69632); // [8][64][8] bf16
    unsigned short* Blo = (unsigned short*)(smem + 77824);

    const int tid  = threadIdx.x;
    const int lane = tid & 63;
    const int w    = tid >> 6;
    const int dir  = blockIdx.x / groups;
    const int g    = blockIdx.x % groups;
    const int nseq = groups * 16;
    const unsigned short* W = dir ? Wb : Wf;
    const float* bh = dir ? bhb : bhf;
    const int t0  = dir ? t0b : t0f;
    const int sgn = dir ? -1 : 1;

    const int j  = tid & 255;          // hidden unit for elementwise phase
    const int sh = (tid >> 8) * 8;     // seq sub-block (8 seqs)
    const float bhr = bh[j], bhz = bh[j + 256], bhn = bh[j + 512];

    // --- W_hh fragments -> registers (rows w*96 .. w*96+95) ---
    bf16x8 wf[6][8];
    {
        const int r0 = w * 96 + (lane & 15);
        const int kf = (lane >> 4) * 8;
        #pragma unroll
        for (int mt = 0; mt < 6; ++mt)
            #pragma unroll
            for (int kk = 0; kk < 8; ++kk)
                wf[mt][kk] = *reinterpret_cast<const bf16x8*>(
                    W + (long)(r0 + mt * 16) * 256 + kk * 32 + kf);
    }

    // --- init h from persistent state ---
    #pragma unroll 4
    for (int e = 0; e < 8; ++e) {
        const int s = sh + e;
        const float h0 = state[((long)dir * nseq + g * 16 + s) * 256 + j];
        hstate[j * 17 + s] = h0;
        const unsigned short hb = f2b(h0);
        const int pos = ((j >> 5) * 64 + ((j >> 3) & 3) * 16 + s) * 8 + (j & 7);
        Bhi[pos] = hb;
        Blo[pos] = f2b(h0 - b2f(hb));
    }
    __syncthreads();

    const long xdir = (long)dir * nseq * steps * 768;

    for (int st = 0; st < steps; ++st) {
        const int t = t0 + sgn * st;

        // ---- MFMA phase: pre = W_hh @ h ----
        floatx4 acc[6];
        #pragma unroll
        for (int mt = 0; mt < 6; ++mt) acc[mt] = (floatx4){0.f, 0.f, 0.f, 0.f};
        #pragma unroll
        for (int kk = 0; kk < 8; ++kk) {
            bf16x8 bhv = *reinterpret_cast<const bf16x8*>(Bhi + (kk * 64 + lane) * 8);
            bf16x8 blv = *reinterpret_cast<const bf16x8*>(Blo + (kk * 64 + lane) * 8);
            #pragma unroll
            for (int mt = 0; mt < 6; ++mt) {
                acc[mt] = __builtin_amdgcn_mfma_f32_16x16x32_bf16(wf[mt][kk], bhv, acc[mt], 0, 0, 0);
                acc[mt] = __builtin_amdgcn_mfma_f32_16x16x32_bf16(wf[mt][kk], blv, acc[mt], 0, 0, 0);
            }
        }
        {
            const int q = lane >> 4, s = lane & 15;
            #pragma unroll
            for (int mt = 0; mt < 6; ++mt) {
                const int row = w * 96 + mt * 16 + q * 4;
                #pragma unroll
                for (int r_ = 0; r_ < 4; ++r_)
                    pre[(row + r_) * 17 + s] = acc[mt][r_];
            }
        }
        __syncthreads();

        // ---- elementwise phase ----
        #pragma unroll 4
        for (int e = 0; e < 8; ++e) {
            const int s = sh + e;
            const long xrow = xdir + ((long)(g * 16 + s) * steps + st) * 768;
            const float xr = xp[xrow + j];
            const float xz = xp[xrow + 256 + j];
            const float xn = xp[xrow + 512 + j];
            const float pr = pre[j * 17 + s];
            const float pz = pre[(j + 256) * 17 + s];
            const float pn = pre[(j + 512) * 17 + s];
            const float hold = hstate[j * 17 + s];
            const float r  = sigmoidf_(xr + pr + bhr);
            const float z  = sigmoidf_(xz + pz + bhz);
            const float nn = tanhf_(xn + r * (pn + bhn));
            const float hnew = (1.f - z) * nn + z * hold;
            hstate[j * 17 + s] = hnew;
            const unsigned short hb = f2b(hnew);
            const unsigned short lb = f2b(hnew - b2f(hb));
            const int pos = ((j >> 5) * 64 + ((j >> 3) & 3) * 16 + s) * 8 + (j & 7);
            Bhi[pos] = hb;
            Blo[pos] = lb;
            const long orow = ((long)(g * 16 + s) * Tout + t) * 512 + dir * 256 + j;
            ohi[orow] = hb;
            olo[orow] = lb;
        }
        __syncthreads();
    }

    // --- save state for next chunk ---
    #pragma unroll 4
    for (int e = 0; e < 8; ++e) {
        const int s = sh + e;
        state[((long)dir * nseq + g * 16 + s) * 256 + j] = hstate[j * 17 + s];
    }
}

// ---------------------------------------------------------------------------
// outv[n][:] = sum_t softmax(score[n*T..])_t * feats[n*T+t][:]  (H=512, fp32)
// feats = bf16 hi/lo (exact fp32). MODE 0: write bf16 hi/lo. MODE 1: fp32.
// ---------------------------------------------------------------------------
template<int MODE>
__global__ __launch_bounds__(256)
void attn_wsum(const float* __restrict__ score,
               const unsigned short* __restrict__ fhi,
               const unsigned short* __restrict__ flo,
               void* __restrict__ o1, void* __restrict__ o2, int T)
{
    const int n = blockIdx.x;
    const int tid = threadIdx.x;
    __shared__ float a[128];
    if (tid < T) a[tid] = score[n * T + tid];
    __syncthreads();
    float mx = -1e30f;
    for (int t = 0; t < T; ++t) mx = fmaxf(mx, a[t]);
    float sm = 0.f;
    for (int t = 0; t < T; ++t) sm += __expf(a[t] - mx);
    const float inv = 1.f / sm;
    float acc0 = 0.f, acc1 = 0.f;
    for (int t = 0; t < T; ++t) {
        const float w = __expf(a[t] - mx) * inv;
        const long base = ((long)n * T + t) * 512;
        acc0 += w * (b2f(fhi[base + tid])       + b2f(flo[base + tid]));
        acc1 += w * (b2f(fhi[base + tid + 256]) + b2f(flo[base + tid + 256]));
    }
    if (MODE == 1) {
        float* o = (float*)o1;
        o[n * 512 + tid] = acc0;
        o[n * 512 + tid + 256] = acc1;
    } else {
        unsigned short* oh = (unsigned short*)o1;
        unsigned short* ol = (unsigned short*)o2;
        const unsigned short h0 = f2b(acc0), h1 = f2b(acc1);
        oh[n * 512 + tid]       = h0;  ol[n * 512 + tid]       = f2b(acc0 - b2f(h0));
        oh[n * 512 + tid + 256] = h1;  ol[n * 512 + tid + 256] = f2b(acc1 - b2f(h1));
    }
}

extern "C" void kernel_launch(void* const* d_in, const int* in_sizes, int n_in,
                              void* d_out, int out_size, void* d_ws, size_t ws_size,
                              hipStream_t stream) {
    const float* tok      = (const float*)d_in[0];
    const float* w_wih_f  = (const float*)d_in[2];
    const float* w_whh_f  = (const float*)d_in[3];
    const float* w_bih_f  = (const float*)d_in[4];
    const float* w_bhh_f  = (const float*)d_in[5];
    const float* w_wih_b  = (const float*)d_in[6];
    const float* w_whh_b  = (const float*)d_in[7];
    const float* w_bih_b  = (const float*)d_in[8];
    const float* w_bhh_b  = (const float*)d_in[9];
    const float* s_wih_f  = (const float*)d_in[10];
    const float* s_whh_f  = (const float*)d_in[11];
    const float* s_bih_f  = (const float*)d_in[12];
    const float* s_bhh_f  = (const float*)d_in[13];
    const float* s_wih_b  = (const float*)d_in[14];
    const float* s_whh_b  = (const float*)d_in[15];
    const float* s_bih_b  = (const float*)d_in[16];
    const float* s_bhh_b  = (const float*)d_in[17];
    const float* w_attn_b = (const float*)d_in[19];
    const float* w_ctx    = (const float*)d_in[20];
    const float* s_attn_b = (const float*)d_in[22];
    const float* s_ctx    = (const float*)d_in[23];

    char* ws = (char*)d_ws;
    float*          xpc   = (float*)(ws + O_XPC);
    unsigned short* owhi  = (unsigned short*)(ws + O_OWHI);
    unsigned short* owlo  = (unsigned short*)(ws + O_OWLO);
    float*          state = (float*)(ws + O_STATE);
    float*          score_w = (float*)(ws + O_SCW);
    unsigned short* W0HI  = (unsigned short*)(ws + O_W0HI);
    unsigned short* W0LO  = (unsigned short*)(ws + O_W0LO);
    unsigned short* W1HI  = (unsigned short*)(ws + O_W1HI);
    unsigned short* W1LO  = (unsigned short*)(ws + O_W1LO);
    unsigned short* WAHI  = (unsigned short*)(ws + O_WAHI);
    unsigned short* WALO  = (unsigned short*)(ws + O_WALO);
    unsigned short* S0HI  = (unsigned short*)(ws + O_S0HI);
    unsigned short* S0LO  = (unsigned short*)(ws + O_S0LO);
    unsigned short* S1HI  = (unsigned short*)(ws + O_S1HI);
    unsigned short* S1LO  = (unsigned short*)(ws + O_S1LO);
    unsigned short* SAHI  = (unsigned short*)(ws + O_SAHI);
    unsigned short* SALO  = (unsigned short*)(ws + O_SALO);
    unsigned short* HW0   = (unsigned short*)(ws + O_HW0);
    unsigned short* HW1   = (unsigned short*)(ws + O_HW1);
    unsigned short* HS0   = (unsigned short*)(ws + O_HS0);
    unsigned short* HS1   = (unsigned short*)(ws + O_HS1);
    unsigned short* senthi = (unsigned short*)(ws + O_SENTHI);
    unsigned short* sentlo = (unsigned short*)(ws + O_SENTLO);
    float*          xp_s  = (float*)(ws + O_XPS);
    float*          sstate = (float*)(ws + O_SSTATE);
    unsigned short* oshi  = (unsigned short*)(ws + O_OSHI);
    unsigned short* oslo  = (unsigned short*)(ws + O_OSLO);
    float*          score_s = (float*)(ws + O_SCS);

    const dim3 blk(256);
    const size_t GRU_LDS = 86016;   // pre 52224 + hstate 17408 + B 2*8192

    // Zero-init: GRU h states and atomic score accumulators.
    hipMemsetAsync(ws + O_STATE,  0, 524288, stream);
    hipMemsetAsync(ws + O_SSTATE, 0, 32768, stream);
    hipMemsetAsync(ws + O_SCW,    0, 131072, stream);
    hipMemsetAsync(ws + O_SCS,    0, 1024, stream);

    // Weight prep.
    cvt_hilo6<<<dim3(1024), blk, 0, stream>>>(w_wih_f, w_wih_b, s_wih_f, s_wih_b,
                                              (const float*)d_in[18], (const float*)d_in[21], ws);
    cvt_b4<<<dim3(384), blk, 0, stream>>>(w_whh_f, w_whh_b, s_whh_f, s_whh_b, ws);

    // Word level: 4 time-chunks of 32 steps.
    const long XDW = 256L * 32 * 768;
    for (int c = 0; c < 4; ++c) {
        gemm<1, 0><<<dim3(12, 128), blk, 0, stream>>>(
            tok, nullptr, W0HI, W0LO, w_bih_f, xpc, 768, nullptr, nullptr,
            512, 32 * c, 1);
        gemm<1, 0><<<dim3(12, 128), blk, 0, stream>>>(
            tok, nullptr, W1HI, W1LO, w_bih_b, xpc + XDW, 768, nullptr, nullptr,
            512, 127 - 32 * c, -1);
        gru_reg<<<dim3(32), dim3(512), GRU_LDS, stream>>>(
            xpc, HW0, HW1, w_bhh_f, w_bhh_b, state, owhi, owlo,
            32, 32 * c, 127 - 32 * c, 16, 128);
    }

    // Word attention: fused u-GEMM + tanh·ctx score, then softmax+wsum.
    gemm<2, 1><<<dim3(8, 512), blk, 0, stream>>>(
        owhi, owlo, WAHI, WALO, w_attn_b, nullptr, 0, score_w, w_ctx, 512, 0, 1);
    attn_wsum<0><<<dim3(256), blk, 0, stream>>>(score_w, owhi, owlo, senthi, sentlo, 128);

    // Sentence input gates.
    const long XDS = 16L * 16 * 768;
    gemm<3, 0><<<dim3(12, 4), blk, 0, stream>>>(
        senthi, sentlo, S0HI, S0LO, s_bih_f, xp_s, 768, nullptr, nullptr,
        512, 0, 1);
    gemm<3, 0><<<dim3(12, 4), blk, 0, stream>>>(
        senthi, sentlo, S1HI, S1LO, s_bih_b, xp_s + XDS, 768, nullptr, nullptr,
        512, 15, -1);

    // Sentence BiGRU: 16 seqs/dir, T=16.
    gru_reg<<<dim3(2), dim3(512), GRU_LDS, stream>>>(
        xp_s, HS0, HS1, s_bhh_f, s_bhh_b, sstate, oshi, oslo,
        16, 0, 15, 1, 16);

    // Sentence attention -> d_out (16 x 512 fp32).
    gemm<2, 1><<<dim3(8, 4), blk, 0, stream>>>(
        oshi, oslo, SAHI, SALO, s_attn_b, nullptr, 0, score_s, s_ctx, 512, 0, 1);
    attn_wsum<1><<<dim3(16), blk, 0, stream>>>(score_s, oshi, oslo, d_out, nullptr, 16);
}